// Round 12
// baseline (458.469 us; speedup 1.0000x reference)
//
#include <hip/hip_runtime.h>

#define H 10
#define T_LEN 2048
#define BATCH 8192

typedef _Float16 f16x4 __attribute__((ext_vector_type(4)));
typedef float f32x4 __attribute__((ext_vector_type(4)));

__device__ __forceinline__ f32x4 mfma16(f16x4 a, f16x4 b, f32x4 c) {
#if __has_builtin(__builtin_amdgcn_mfma_f32_16x16x16f16)
    return __builtin_amdgcn_mfma_f32_16x16x16f16(a, b, c, 0, 0, 0);
#else
    f32x4 d;
    asm("v_mfma_f32_16x16x16_f16 %0, %1, %2, %3"
        : "=v"(d) : "v"(a), "v"(b), "v"(c));
    return d;
#endif
}

// ---------------------------------------------------------------------------
// Single fused kernel, MFMA recurrence (R11 structure, precision fixed).
//
// Geometry (16x16x16 f16 MFMA, D=A*B+C):
//   A-operand: lane l holds A[row j = l&15][k = (l>>4)*4+s], s=0..3
//   B-operand: lane l holds B[k = (l>>4)*4+s][col b = l&15]
//   C/D      : lane l holds D[row j = (l>>4)*4+s][col b = l&15]
// With A := Bmat^T and B-operand := h per batch-column, D = Bmat^T·h and
// D's rows per lane EQUAL the B-operand k-slots per lane: the 2048-step
// recurrence is 100% lane-local (no DPP / LDS / shuffle — R1-R10 measured
// cross-lane transport at >=11 cy/batch-step; this removes it).
// R11's 3.1% error == sqrt(2048)*2^-11: it dropped the FIRST-ORDER terms
// A_hi·h_lo + A_lo·h_hi. Fix: 3 MFMAs keep all first-order terms; only
// A_lo·h_lo (2^-22 rel/step -> ~1e-5 compounded) is dropped.
//
// One wave serves 16 batches; 512 blocks x 64 threads.
// ---------------------------------------------------------------------------
__global__ __launch_bounds__(64)
void rnn_kernel(const float* __restrict__ x,
                const float* __restrict__ A,
                const float* __restrict__ Win,
                const float* __restrict__ bmod,
                const float* __restrict__ lW,
                const float* __restrict__ lb,
                float* __restrict__ out) {
    __shared__ double S[H][H];
    __shared__ double Pm[H][H];
    __shared__ double E[H][H];
    __shared__ float hsh[16][16];     // [comp][batch] for the epilogue
    const int tid = threadIdx.x;

    // ---- expm(skew(A)) fp64: scale 2^-8, 16 Taylor terms, 8 squarings
    // (verified R8/R9: bit-identical to the original standalone kernel).
    {
        const int e0 = tid, e1 = tid + 64;
        const int i0 = e0 / H, j0 = e0 % H;
        const int i1 = e1 / H, j1 = e1 % H;
        const bool v1 = (e1 < H * H);
        double a0 = 0.0;
        if (i0 < j0) a0 = (double)A[i0 * H + j0];
        else if (i0 > j0) a0 = -(double)A[j0 * H + i0];
        a0 *= (1.0 / 256.0);
        S[i0][j0] = a0; Pm[i0][j0] = a0;
        E[i0][j0] = (i0 == j0 ? 1.0 : 0.0) + a0;
        if (v1) {
            double a1 = 0.0;
            if (i1 < j1) a1 = (double)A[i1 * H + j1];
            else if (i1 > j1) a1 = -(double)A[j1 * H + i1];
            a1 *= (1.0 / 256.0);
            S[i1][j1] = a1; Pm[i1][j1] = a1;
            E[i1][j1] = (i1 == j1 ? 1.0 : 0.0) + a1;
        }
        __syncthreads();
        for (int k = 2; k <= 16; ++k) {
            double t0 = 0.0, t1 = 0.0;
            for (int m = 0; m < H; ++m) t0 += Pm[i0][m] * S[m][j0];
            t0 *= (1.0 / (double)k);
            if (v1) {
                for (int m = 0; m < H; ++m) t1 += Pm[i1][m] * S[m][j1];
                t1 *= (1.0 / (double)k);
            }
            __syncthreads();
            Pm[i0][j0] = t0; E[i0][j0] += t0;
            if (v1) { Pm[i1][j1] = t1; E[i1][j1] += t1; }
            __syncthreads();
        }
        for (int rr = 0; rr < 8; ++rr) {
            double t0 = 0.0, t1 = 0.0;
            for (int m = 0; m < H; ++m) t0 += E[i0][m] * E[m][j0];
            if (v1) {
                for (int m = 0; m < H; ++m) t1 += E[i1][m] * E[m][j1];
            }
            __syncthreads();
            E[i0][j0] = t0;
            if (v1) E[i1][j1] = t1;
            __syncthreads();
        }
    }

    // ---- fragment setup
    const int l15  = tid & 15;        // A: row j  |  B/D: batch column
    const int rrow = tid >> 4;        // 0..3: k/row quad
    const int bb   = blockIdx.x * 16 + l15;   // this lane's batch (B/D view)

    // A = Bmat^T split hi+lo: A[j=l15][m=rrow*4+s] = E[m][l15]; 0 on pads.
    f16x4 a_hi, a_lo;
#pragma unroll
    for (int s = 0; s < 4; ++s) {
        const int m = rrow * 4 + s;
        float av = (m < H && l15 < H) ? (float)E[m][l15] : 0.f;
        _Float16 ah = (_Float16)av;
        a_hi[s] = ah;
        a_lo[s] = (_Float16)(av - (float)ah);
    }
    // per-lane xproj/modrelu constants for OWNED comps j4 = rrow*4+s (D rows)
    float w0v[4], w1v[4], bmv[4];
#pragma unroll
    for (int s = 0; s < 4; ++s) {
        const int j4 = rrow * 4 + s;
        w0v[s] = (j4 < H) ? Win[j4 * 2]     : 0.f;
        w1v[s] = (j4 < H) ? Win[j4 * 2 + 1] : 0.f;
        bmv[s] = (j4 < H) ? bmod[j4]        : 0.f;
    }

    f16x4 hhi = {};   // h = 0
    f16x4 hlo = {};
    f32x4 hf  = {};   // f32 copy of owned h comps (for epilogue)

    const float4* __restrict__ xp4 = (const float4*)(x + (size_t)bb * (T_LEN * 2));
    float4 cur[4], nxt[4];
#pragma unroll
    for (int i = 0; i < 4; ++i) cur[i] = xp4[i];

    for (int t0 = 0; t0 < T_LEN; t0 += 8) {
        if (t0 + 8 < T_LEN) {
            const int base = (t0 + 8) >> 1;
#pragma unroll
            for (int i = 0; i < 4; ++i) nxt[i] = xp4[base + i];
        }
#pragma unroll
        for (int u = 0; u < 8; ++u) {
            const int ii = u >> 1;
            const float x0 = (u & 1) ? cur[ii].z : cur[ii].x;
            const float x1 = (u & 1) ? cur[ii].w : cur[ii].y;

            // C seed = xproj for owned comps (C layout == D layout)
            f32x4 c;
#pragma unroll
            for (int s = 0; s < 4; ++s)
                c[s] = fmaf(x1, w1v[s], x0 * w0v[s]);

            // matvec with all first-order terms:
            // D = A_hi·h_hi + A_lo·h_hi + A_hi·h_lo + xproj
            f32x4 d = mfma16(a_hi, hhi, c);
            d = mfma16(a_lo, hhi, d);
            d = mfma16(a_hi, hlo, d);

            // modrelu + hi/lo split (all lane-local)
#pragma unroll
            for (int s = 0; s < 4; ++s) {
                const float sv = d[s];
                const float r  = fmaxf(fabsf(sv) + bmv[s], 0.f);
                const float h  = __builtin_copysignf(r, sv);
                hf[s] = h;
                const _Float16 hh = (_Float16)h;
                hhi[s] = hh;
                hlo[s] = (_Float16)(h - (float)hh);
            }
        }
#pragma unroll
        for (int i = 0; i < 4; ++i) cur[i] = nxt[i];
    }

    // ---- epilogue: gather h via LDS, out[b][comp] = lb + h·lW[comp][:]
    __syncthreads();   // expm LDS reuse barrier (E no longer needed)
#pragma unroll
    for (int s = 0; s < 4; ++s) hsh[rrow * 4 + s][l15] = hf[s];
    __syncthreads();
    for (int i = tid; i < 16 * H; i += 64) {
        const int b = i / H, comp = i - b * H;
        float acc = lb[comp];
#pragma unroll
        for (int m = 0; m < H; ++m)
            acc = fmaf(hsh[m][b], lW[comp * H + m], acc);
        out[(size_t)(blockIdx.x * 16 + b) * H + comp] = acc;
    }
}

extern "C" void kernel_launch(void* const* d_in, const int* in_sizes, int n_in,
                              void* d_out, int out_size, void* d_ws, size_t ws_size,
                              hipStream_t stream) {
    const float* inputs = (const float*)d_in[0];  // [8192, 2048, 2]
    const float* A      = (const float*)d_in[1];  // [10, 10]
    const float* W_in   = (const float*)d_in[2];  // [10, 2]
    const float* b_mod  = (const float*)d_in[3];  // [10]
    const float* lin_W  = (const float*)d_in[4];  // [10, 10]
    const float* lin_b  = (const float*)d_in[5];  // [10]
    float* out = (float*)d_out;                   // [8192, 10]
    (void)d_ws; (void)ws_size;

    rnn_kernel<<<BATCH / 16, 64, 0, stream>>>(inputs, A, W_in, b_mod,
                                              lin_W, lin_b, out);
}